// Round 3
// baseline (1199.802 us; speedup 1.0000x reference)
//
#include <hip/hip_runtime.h>

// DenseDilatedKnnGraph: B=4, C=64, N=4096, K=9, DILATION=2 (k_eff=18)
// Input  d_in[0]: float32 (B, C, N, 1)  -> x[b][c][n] at ((b*64)+c)*4096 + n
// Output d_out:   int32   (2, B, N, 9)  -> [0]=neighbor idx (ranks 0,2,..,16), [1]=center n
//
// Grading ref is numpy fp32 ("ref=np") recompute; round 2 passed with absmax 0
// by emulating numpy's fp32 arithmetic BIT-EXACTLY:
//  - einsum dot: sequential c-ascending fp32 accumulate, SEPARATE mul/add
//    roundings (no FMA) -> #pragma clang fp contract(off)
//  - x_square: numpy pairwise-sum AVX512 tree for n=64
//  - key = fl(fl(sq_n + fl(-2*d)) + sq_m); ties -> lower index
// This round: same numerics, restructured for VALU-issue efficiency:
//  - Q=4 queries per block: m-data loads + addressing amortized 4x
//  - thread owns m = 16*t+j (contiguous) -> 4x global_load_dwordx4 per c
//    (was 16 scalar loads at stride 256)
//  - selection: running per-thread argmin + owner-only rescan, parity
//    double-buffered LDS reduce -> 1 barrier/round, rank capture in regs

#pragma clang fp contract(off)

#define BB    4
#define CDIM  64
#define NPTS  4096
#define KSEL  17   // need sorted positions 0..16 (every 2nd of top-18)
#define KOUT  9
#define QB    4

__global__ __launch_bounds__(256) void knn_sq(const float* __restrict__ x,
                                              float* __restrict__ sq) {
#pragma clang fp contract(off)
    int g = blockIdx.x * 256 + threadIdx.x;       // g = b*NPTS + m
    int b = g >> 12;
    int m = g & (NPTS - 1);
    const float* xb = x + (size_t)b * CDIM * NPTS + m;

    float a[CDIM];
    #pragma unroll
    for (int c = 0; c < CDIM; ++c) {
        float v = xb[c * NPTS];
        a[c] = v * v;
    }
    // numpy pairwise_sum, AVX512 (16-lane) path for n=64:
    float s16[16];
    #pragma unroll
    for (int i = 0; i < 16; ++i)
        s16[i] = (a[i] + a[i + 16]) + (a[i + 32] + a[i + 48]);
    float t8[8];
    #pragma unroll
    for (int i = 0; i < 8; ++i) t8[i] = s16[i] + s16[i + 8];
    float t4[4];
    #pragma unroll
    for (int i = 0; i < 4; ++i) t4[i] = t8[i] + t8[i + 4];
    float u0 = t4[0] + t4[2];
    float u1 = t4[1] + t4[3];
    sq[g] = u0 + u1;
}

__global__ __launch_bounds__(256, 4) void knn_main(const float* __restrict__ x,
                                                   const float* __restrict__ sq,
                                                   int* __restrict__ out) {
#pragma clang fp contract(off)
    const int blk = blockIdx.x;                   // 1024 blocks per b
    const int b   = blk >> 10;
    const int n0  = (blk & 1023) * QB;
    const int t   = threadIdx.x;

    __shared__ float qs[QB][CDIM];
    __shared__ float redD[2][4];
    __shared__ int   redI[2][4];

    const float* xb = x + (size_t)b * CDIM * NPTS;

    // load the 4 query vectors (QB*CDIM == 256 values, one per thread)
    {
        int q = t >> 6, c = t & 63;
        qs[q][c] = xb[c * NPTS + n0 + q];
    }
    __syncthreads();

    const float* sqb = sq + (b << 12);

    // ---- fp32 dots, c ascending, separate mul/add roundings ----
    // thread owns m = 16*t + j, j in [0,16)
    float acc[QB][16];
    {
        const float4* xr = (const float4*)(xb + 16 * t);
        float4 v0 = xr[0], v1 = xr[1], v2 = xr[2], v3 = xr[3];
        float xv[16] = {v0.x, v0.y, v0.z, v0.w, v1.x, v1.y, v1.z, v1.w,
                        v2.x, v2.y, v2.z, v2.w, v3.x, v3.y, v3.z, v3.w};
        #pragma unroll
        for (int q = 0; q < QB; ++q) {
            float qc = qs[q][0];
            #pragma unroll
            for (int j = 0; j < 16; ++j) acc[q][j] = qc * xv[j];  // fl(q*x) == 0+p
        }
    }
    #pragma unroll 2
    for (int c = 1; c < CDIM; ++c) {
        const float4* xr = (const float4*)(xb + c * NPTS + 16 * t);
        float4 v0 = xr[0], v1 = xr[1], v2 = xr[2], v3 = xr[3];
        float xv[16] = {v0.x, v0.y, v0.z, v0.w, v1.x, v1.y, v1.z, v1.w,
                        v2.x, v2.y, v2.z, v2.w, v3.x, v3.y, v3.z, v3.w};
        #pragma unroll
        for (int q = 0; q < QB; ++q) {
            float qc = qs[q][c];
            #pragma unroll
            for (int j = 0; j < 16; ++j) {
                float p = qc * xv[j];             // fl(q*x)
                acc[q][j] = acc[q][j] + p;        // fl(d+p)  (no FMA!)
            }
        }
    }

    float sqm[16];
    {
        const float4* sr = (const float4*)(sqb + 16 * t);
        float4 s0 = sr[0], s1 = sr[1], s2 = sr[2], s3 = sr[3];
        sqm[0]=s0.x; sqm[1]=s0.y; sqm[2]=s0.z; sqm[3]=s0.w;
        sqm[4]=s1.x; sqm[5]=s1.y; sqm[6]=s1.z; sqm[7]=s1.w;
        sqm[8]=s2.x; sqm[9]=s2.y; sqm[10]=s2.z; sqm[11]=s2.w;
        sqm[12]=s3.x; sqm[13]=s3.y; sqm[14]=s3.z; sqm[15]=s3.w;
    }

    // ---- per-query: key transform (in place) + top-17 selection ----
    #pragma unroll
    for (int q = 0; q < QB; ++q) {
        const float sqn = sqb[n0 + q];
        #pragma unroll
        for (int j = 0; j < 16; ++j) {
            float inner = -2.0f * acc[q][j];      // exact scaling
            float t1    = sqn + inner;
            acc[q][j]   = t1 + sqm[j];            // key = fl(fl(sqn+fl(-2d))+sqm)
        }

        // running per-thread argmin over alive keys (j ascending => lowest m on ties)
        unsigned mask = 0;
        float cm = 3.0e38f;
        int   ci = 0x7fffffff;
        #pragma unroll
        for (int j = 0; j < 16; ++j) {
            float v = acc[q][j];
            if (v < cm) { cm = v; ci = 16 * t + j; }
        }

        int myOut = 0;
        for (int r = 0; r < KSEL; ++r) {
            const int p = (q + r) & 1;            // (q*17+r)&1, since 17 is odd
            float bd = cm;
            int   bi = ci;
            #pragma unroll
            for (int off = 32; off >= 1; off >>= 1) {
                float od = __shfl_down(bd, off);
                int   oi = __shfl_down(bi, off);
                if (od < bd || (od == bd && oi < bi)) { bd = od; bi = oi; }
            }
            if ((t & 63) == 0) { redD[p][t >> 6] = bd; redI[p][t >> 6] = bi; }
            __syncthreads();
            float gb = redD[p][0];
            int   gi = redI[p][0];
            #pragma unroll
            for (int w = 1; w < 4; ++w) {
                float od = redD[p][w];
                int   oi = redI[p][w];
                if (od < gb || (od == gb && oi < gi)) { gb = od; gi = oi; }
            }
            if (t < KOUT && r == 2 * t) myOut = gi;   // capture even ranks
            if ((gi >> 4) == t) {                      // owner: mask + rescan
                mask |= 1u << (gi & 15);
                cm = 3.0e38f; ci = 0x7fffffff;
                #pragma unroll
                for (int j = 0; j < 16; ++j) {
                    float v = acc[q][j];
                    if (!((mask >> j) & 1u) && v < cm) { cm = v; ci = 16 * t + j; }
                }
            }
        }

        if (t < KOUT) {
            int    nq   = n0 + q;
            size_t base = (size_t)((b << 12) + nq) * KOUT;
            out[base + t] = myOut;
            out[(size_t)BB * NPTS * KOUT + base + t] = nq;
        }
    }
}

extern "C" void kernel_launch(void* const* d_in, const int* in_sizes, int n_in,
                              void* d_out, int out_size, void* d_ws, size_t ws_size,
                              hipStream_t stream) {
    const float* x   = (const float*)d_in[0];
    float*       sqv = (float*)d_ws;              // 4*4096*4 = 65536 B
    int*         out = (int*)d_out;

    hipLaunchKernelGGL(knn_sq,   dim3((BB * NPTS) / 256), dim3(256), 0, stream, x, sqv);
    hipLaunchKernelGGL(knn_main, dim3((BB * NPTS) / QB),  dim3(256), 0, stream, x, sqv, out);
}

// Round 4
// 543.044 us; speedup vs baseline: 2.2094x; 2.2094x over previous
//
#include <hip/hip_runtime.h>

// DenseDilatedKnnGraph: B=4, C=64, N=4096, K=9, DILATION=2 (k_eff=18)
// Input  d_in[0]: float32 (B, C, N, 1)  -> x[b][c][n] at ((b*64)+c)*4096 + n
// Output d_out:   int32   (2, B, N, 9)  -> [0]=neighbor idx (ranks 0,2,..,16), [1]=center n
//
// Grading ref is a numpy fp32 recompute ("ref=np"); we match it BIT-EXACTLY:
//  - einsum dot: sequential c-ascending fp32 accumulate, SEPARATE mul/add
//    roundings (no FMA) -> #pragma clang fp contract(off)
//  - x_square: numpy pairwise-sum AVX512 tree for n=64
//  - key = fl(fl(sq_n + fl(-2*d)) + sq_m); ties -> lower index
//
// Round-3 post-mortem: QB=4 with acc[QB][16] spilled to scratch (WRITE_SIZE
// 3.5 GB, VGPR 64, VALUBusy 25%) because the q-selection loop (barriers in
// body) wasn't unrolled -> runtime-indexed array -> local memory (rule #20).
// Round 4: QB=2 with NAMED acc0/acc1 arrays and the per-query selection
// stamped out via macro, so every register-array index is a compile-time
// constant. Keeps 2x load amortization + dwordx4 m-ownership (m = 16*t+j).

#pragma clang fp contract(off)

#define BB    4
#define CDIM  64
#define NPTS  4096
#define KSEL  17   // need sorted positions 0..16 (every 2nd of top-18)
#define KOUT  9
#define QB    2

__global__ __launch_bounds__(256) void knn_sq(const float* __restrict__ x,
                                              float* __restrict__ sq) {
#pragma clang fp contract(off)
    int g = blockIdx.x * 256 + threadIdx.x;       // g = b*NPTS + m
    int b = g >> 12;
    int m = g & (NPTS - 1);
    const float* xb = x + (size_t)b * CDIM * NPTS + m;

    float a[CDIM];
    #pragma unroll
    for (int c = 0; c < CDIM; ++c) {
        float v = xb[c * NPTS];
        a[c] = v * v;
    }
    // numpy pairwise_sum, AVX512 (16-lane) path for n=64:
    float s16[16];
    #pragma unroll
    for (int i = 0; i < 16; ++i)
        s16[i] = (a[i] + a[i + 16]) + (a[i + 32] + a[i + 48]);
    float t8[8];
    #pragma unroll
    for (int i = 0; i < 8; ++i) t8[i] = s16[i] + s16[i + 8];
    float t4[4];
    #pragma unroll
    for (int i = 0; i < 4; ++i) t4[i] = t8[i] + t8[i + 4];
    float u0 = t4[0] + t4[2];
    float u1 = t4[1] + t4[3];
    sq[g] = u0 + u1;
}

// Per-query key transform + top-17 selection. ACC is a NAMED float[16]
// (compile-time indexed everywhere). QI is a literal 0/1.
#define DO_QUERY(ACC, QI)                                                      \
    {                                                                          \
        const float sqn = sqb[n0 + (QI)];                                      \
        _Pragma("unroll")                                                      \
        for (int j = 0; j < 16; ++j) {                                         \
            float inner = -2.0f * ACC[j];       /* exact scaling */            \
            float t1    = sqn + inner;                                         \
            ACC[j]      = t1 + sqm[j];          /* fl(fl(sqn+fl(-2d))+sqm) */  \
        }                                                                      \
        unsigned mask = 0;                                                     \
        float cm = 3.0e38f;                                                    \
        int   ci = 0x7fffffff;                                                 \
        _Pragma("unroll")                                                      \
        for (int j = 0; j < 16; ++j) {                                         \
            float v = ACC[j];                                                  \
            if (v < cm) { cm = v; ci = 16 * t + j; }                           \
        }                                                                      \
        int myOut = 0;                                                         \
        for (int r = 0; r < KSEL; ++r) {                                       \
            const int p = ((QI) + r) & 1;       /* (q*17+r)&1, 17 odd */       \
            float bd = cm;                                                     \
            int   bi = ci;                                                     \
            _Pragma("unroll")                                                  \
            for (int off = 32; off >= 1; off >>= 1) {                          \
                float od = __shfl_down(bd, off);                               \
                int   oi = __shfl_down(bi, off);                               \
                if (od < bd || (od == bd && oi < bi)) { bd = od; bi = oi; }    \
            }                                                                  \
            if ((t & 63) == 0) { redD[p][t >> 6] = bd; redI[p][t >> 6] = bi; } \
            __syncthreads();                                                   \
            float gb = redD[p][0];                                             \
            int   gi = redI[p][0];                                             \
            _Pragma("unroll")                                                  \
            for (int w = 1; w < 4; ++w) {                                      \
                float od = redD[p][w];                                         \
                int   oi = redI[p][w];                                         \
                if (od < gb || (od == gb && oi < gi)) { gb = od; gi = oi; }    \
            }                                                                  \
            if (t < KOUT && r == 2 * t) myOut = gi;  /* capture even ranks */  \
            if ((gi >> 4) == t) {                    /* owner: mask+rescan */  \
                mask |= 1u << (gi & 15);                                       \
                cm = 3.0e38f; ci = 0x7fffffff;                                 \
                _Pragma("unroll")                                              \
                for (int j = 0; j < 16; ++j) {                                 \
                    float v = ACC[j];                                          \
                    if (!((mask >> j) & 1u) && v < cm) { cm = v; ci = 16 * t + j; } \
                }                                                              \
            }                                                                  \
        }                                                                      \
        if (t < KOUT) {                                                        \
            int    nq   = n0 + (QI);                                           \
            size_t base = (size_t)((b << 12) + nq) * KOUT;                     \
            out[base + t] = myOut;                                             \
            out[(size_t)BB * NPTS * KOUT + base + t] = nq;                     \
        }                                                                      \
    }

__global__ __launch_bounds__(256, 4) void knn_main(const float* __restrict__ x,
                                                   const float* __restrict__ sq,
                                                   int* __restrict__ out) {
#pragma clang fp contract(off)
    const int blk = blockIdx.x;                   // 2048 blocks per b
    const int b   = blk >> 11;
    const int n0  = (blk & 2047) * QB;
    const int t   = threadIdx.x;

    __shared__ float qs[QB][CDIM];
    __shared__ float redD[2][4];
    __shared__ int   redI[2][4];

    const float* xb = x + (size_t)b * CDIM * NPTS;

    // load the 2 query vectors (QB*CDIM == 128 values)
    if (t < QB * CDIM) {
        int q = t >> 6, c = t & 63;
        qs[q][c] = xb[c * NPTS + n0 + q];
    }
    __syncthreads();

    const float* sqb = sq + (b << 12);

    // ---- fp32 dots, c ascending, separate mul/add roundings ----
    // thread owns m = 16*t + j, j in [0,16)
    float acc0[16], acc1[16];
    {
        const float4* xr = (const float4*)(xb + 16 * t);
        float4 v0 = xr[0], v1 = xr[1], v2 = xr[2], v3 = xr[3];
        float xv[16] = {v0.x, v0.y, v0.z, v0.w, v1.x, v1.y, v1.z, v1.w,
                        v2.x, v2.y, v2.z, v2.w, v3.x, v3.y, v3.z, v3.w};
        float q0 = qs[0][0], q1 = qs[1][0];
        #pragma unroll
        for (int j = 0; j < 16; ++j) {
            acc0[j] = q0 * xv[j];                 // fl(q*x) == 0+p
            acc1[j] = q1 * xv[j];
        }
    }
    #pragma unroll 2
    for (int c = 1; c < CDIM; ++c) {
        const float4* xr = (const float4*)(xb + c * NPTS + 16 * t);
        float4 v0 = xr[0], v1 = xr[1], v2 = xr[2], v3 = xr[3];
        float xv[16] = {v0.x, v0.y, v0.z, v0.w, v1.x, v1.y, v1.z, v1.w,
                        v2.x, v2.y, v2.z, v2.w, v3.x, v3.y, v3.z, v3.w};
        float q0 = qs[0][c], q1 = qs[1][c];
        #pragma unroll
        for (int j = 0; j < 16; ++j) {
            float p0 = q0 * xv[j];                // fl(q*x)
            acc0[j] = acc0[j] + p0;               // fl(d+p)  (no FMA!)
            float p1 = q1 * xv[j];
            acc1[j] = acc1[j] + p1;
        }
    }

    float sqm[16];
    {
        const float4* sr = (const float4*)(sqb + 16 * t);
        float4 s0 = sr[0], s1 = sr[1], s2 = sr[2], s3 = sr[3];
        sqm[0]=s0.x; sqm[1]=s0.y; sqm[2]=s0.z; sqm[3]=s0.w;
        sqm[4]=s1.x; sqm[5]=s1.y; sqm[6]=s1.z; sqm[7]=s1.w;
        sqm[8]=s2.x; sqm[9]=s2.y; sqm[10]=s2.z; sqm[11]=s2.w;
        sqm[12]=s3.x; sqm[13]=s3.y; sqm[14]=s3.z; sqm[15]=s3.w;
    }

    DO_QUERY(acc0, 0)
    DO_QUERY(acc1, 1)
}

extern "C" void kernel_launch(void* const* d_in, const int* in_sizes, int n_in,
                              void* d_out, int out_size, void* d_ws, size_t ws_size,
                              hipStream_t stream) {
    const float* x   = (const float*)d_in[0];
    float*       sqv = (float*)d_ws;              // 4*4096*4 = 65536 B
    int*         out = (int*)d_out;

    hipLaunchKernelGGL(knn_sq,   dim3((BB * NPTS) / 256), dim3(256), 0, stream, x, sqv);
    hipLaunchKernelGGL(knn_main, dim3((BB * NPTS) / QB),  dim3(256), 0, stream, x, sqv, out);
}